// Round 4
// baseline (118.135 us; speedup 1.0000x reference)
//
#include <hip/hip_runtime.h>

// MaskedQueryAndGroup — masked ordered ball query + grouping.
// Shapes: B=4, NPOINT=2048, N=8192, C=64, NSAMPLE=32, R=0.1.
//
// Evidence log:
//  R1-R3: fp32 dataset; masks readable as int32; out = new_features
//    (B,67,NPOINT,32) ++ idx_mask (B,NPOINT,32), both f32.
//  R4 PASSED absmax 0.0: dot = fma(qz,z,fma(qy,y,qx*x)), ss/qq plain mul+add,
//    d2=(qq+ss)-2*dot, contract off. DO NOT change d2 arithmetic.
//  R5 FAILED: shfl_up+binary-search load balancer lost candidates. Avoid.
//  R6 PASSED 159.5: grid + x-run enumeration + bitonic sort all verified.
//  R7 PASSED 129.1: parallel build + feat transpose + LDS-bounce gather.
//  R8 PASSED 123.3: gather via per-(b,ch)-row LDS bounce; transpose killed.
//    Harness fixed cost ~60 us/bench (ws 285MB + out 70MB poison fills).
//  R9 PASSED 116.6 (pred 100): fused build + balanced 16-run enumeration.
//  R10 PASSED 114.6 (pred 104): barrier-free query + per-run prune + pipeline.
//    Lesson: query was never ~40us; controllable ~54us is spread across
//    build(~7, 4-block latency) + query(~10) + gather(~15) + overhead.
//  R11 FAILED COMPILE: __builtin_nontemporal_* rejects HIP_vector_type
//    (float4). Fix: clang ext_vector_type(4) float — same 16B layout.
//  R12 (this) = R11 + fix: (a) build phase-1 float4/int4 vectorized loads
//    (8 consecutive pts/thread; within-cell pts order changes — harmless,
//    sort-invariant). (b) gather QCHUNK=2048@512thr: row read once, idx
//    aggregate 64->16MB, nontemporal stores (out never re-read).
//    (c) query: split start/end loads across lane halves + shfl — one
//    dependent L2 round instead of two. Predict 114.6 -> ~109.

#define NPOINT 2048
#define NSUP   8192
#define NCH    64
#define NS     32
#define GRID1  10
#define CELLS  1000   // 10*10*10
#define QCHUNK 2048   // queries per gather block (= NPOINT: row read once)

typedef float nvec4 __attribute__((ext_vector_type(4)));   // nontemporal-ok

// ---------- helpers ----------
__device__ __forceinline__ bool probe_mask4(const void* mask) {
    // int32/f32 masks have byte 4i+1 == 0 always; byte bools ~90% nonzero.
    const unsigned char* mb = (const unsigned char*)mask;
    const int lane = threadIdx.x & 63;
    return __ballot(mb[4 * lane + 1] != 0) == 0ull;
}
__device__ __forceinline__ bool read_mask(const void* mask, int i, bool is4) {
    return is4 ? (((const int*)mask)[i] != 0)
               : (((const unsigned char*)mask)[i] != 0);
}
__device__ __forceinline__ int cell_of(float x, float y, float z) {
    const int cx = min(GRID1 - 1, (int)(x * 10.0f));
    const int cy = min(GRID1 - 1, (int)(y * 10.0f));
    const int cz = min(GRID1 - 1, (int)(z * 10.0f));
    return cx + GRID1 * cy + GRID1 * GRID1 * cz;
}

// ---------- fused build: hist + scan + fill in one kernel (1 block/batch) ----
__global__ __launch_bounds__(1024) void build_grid(
    const float* __restrict__ support_xyz, const void* __restrict__ support_mask,
    int* __restrict__ starts, float4* __restrict__ pts)
{
    __shared__ int hist[CELLS];
    __shared__ int scanb[CELLS];
    __shared__ int cur[CELLS];
    __shared__ int wavesum[16];
    const int b    = blockIdx.x;
    const int tid  = threadIdx.x;
    const int wid  = tid >> 6;
    const int lane = tid & 63;
    const bool m4 = probe_mask4(support_mask);
    const float* sx = support_xyz + (size_t)b * 3 * NSUP;

    if (tid < CELLS) { hist[tid] = 0; cur[tid] = 0; }
    __syncthreads();

    // 8 CONSECUTIVE points per thread via vector loads (G13).
    const float4* x4 = (const float4*)sx;
    const float4* y4 = (const float4*)(sx + NSUP);
    const float4* z4 = (const float4*)(sx + 2 * NSUP);
    const float4 xa = x4[tid * 2], xb = x4[tid * 2 + 1];
    const float4 ya = y4[tid * 2], yb = y4[tid * 2 + 1];
    const float4 za = z4[tid * 2], zb = z4[tid * 2 + 1];
    unsigned mk;
    if (m4) {
        const int4* mi4 = (const int4*)((const int*)support_mask + (size_t)b * NSUP);
        const int4 ma = mi4[tid * 2], mb2 = mi4[tid * 2 + 1];
        mk = (ma.x  != 0 ? 1u   : 0u) | (ma.y  != 0 ? 2u   : 0u)
           | (ma.z  != 0 ? 4u   : 0u) | (ma.w  != 0 ? 8u   : 0u)
           | (mb2.x != 0 ? 16u  : 0u) | (mb2.y != 0 ? 32u  : 0u)
           | (mb2.z != 0 ? 64u  : 0u) | (mb2.w != 0 ? 128u : 0u);
    } else {
        const unsigned char* mb = (const unsigned char*)support_mask
                                + (size_t)b * NSUP + (size_t)tid * 8;
        const unsigned lo = *(const unsigned*)(mb);
        const unsigned hi = *(const unsigned*)(mb + 4);
        mk = ((lo & 0xffu)        ? 1u   : 0u) | ((lo & 0xff00u)     ? 2u   : 0u)
           | ((lo & 0xff0000u)    ? 4u   : 0u) | ((lo & 0xff000000u) ? 8u   : 0u)
           | ((hi & 0xffu)        ? 16u  : 0u) | ((hi & 0xff00u)     ? 32u  : 0u)
           | ((hi & 0xff0000u)    ? 64u  : 0u) | ((hi & 0xff000000u) ? 128u : 0u);
    }
    const float xr[8] = {xa.x, xa.y, xa.z, xa.w, xb.x, xb.y, xb.z, xb.w};
    const float yr[8] = {ya.x, ya.y, ya.z, ya.w, yb.x, yb.y, yb.z, yb.w};
    const float zr[8] = {za.x, za.y, za.z, za.w, zb.x, zb.y, zb.z, zb.w};
    int cidr[8];
    #pragma unroll
    for (int i = 0; i < 8; ++i) {
        cidr[i] = cell_of(xr[i], yr[i], zr[i]);
        if ((mk >> i) & 1u) atomicAdd(&hist[cidr[i]], 1);
    }
    __syncthreads();

    // 3-level wave scan (2 barriers): wave-scan64 -> scan16 sums -> add base
    int v = (tid < CELLS) ? hist[tid] : 0;
    #pragma unroll
    for (int d = 1; d < 64; d <<= 1) {
        const int u = __shfl_up(v, d, 64);
        if (lane >= d) v += u;
    }
    if (lane == 63) wavesum[wid] = v;
    __syncthreads();
    if (wid == 0) {
        int w = (lane < 16) ? wavesum[lane] : 0;
        #pragma unroll
        for (int d = 1; d < 16; d <<= 1) {
            const int u = __shfl_up(w, d, 64);
            if (lane >= d) w += u;
        }
        if (lane < 16) wavesum[lane] = w;
    }
    __syncthreads();
    if (wid > 0) v += wavesum[wid - 1];
    // starts[b][0]=0; starts[b][c+1]=inclusive_sum(counts[0..c])
    int* stg = starts + b * (CELLS + 1);
    if (tid == 0) stg[0] = 0;
    if (tid < CELLS) { stg[tid + 1] = v; scanb[tid] = v; }
    __syncthreads();

    // fill via LDS cursors (within-cell order arbitrary; sort-invariant)
    #pragma unroll
    for (int i = 0; i < 8; ++i) {
        if ((mk >> i) & 1u) {
            const int c    = cidr[i];
            const int base = (c == 0) ? 0 : scanb[c - 1];
            const int pos  = base + atomicAdd(&cur[c], 1);
            pts[(size_t)b * NSUP + pos] =
                make_float4(xr[i], yr[i], zr[i], __int_as_float(tid * 8 + i));
        }
    }
}

// ---------- query: pruned balanced scan + sort, barrier-free (4 q/block) ----
__global__ __launch_bounds__(256) void mqag_query(
    const float* __restrict__ query_xyz, const float* __restrict__ support_xyz,
    const void* __restrict__ query_mask, const void* __restrict__ support_mask,
    const float4* __restrict__ pts, const int* __restrict__ starts,
    int* __restrict__ idx_ws, float* __restrict__ out, int B)
{
#pragma clang fp contract(off)
    const int wib  = threadIdx.x >> 6;
    const int lane = threadIdx.x & 63;
    const int qid  = blockIdx.x * 4 + wib;
    const int b    = qid / NPOINT;
    const int p    = qid % NPOINT;

    // wave-private LDS slices: NO block barriers anywhere in this kernel.
    __shared__ int hits_all[4][64];
    __shared__ int slots_all[4][NS];
    int* hits  = hits_all[wib];
    int* slots = slots_all[wib];

    const bool m4q = probe_mask4(query_mask);

    const float* sx = support_xyz + (size_t)b * 3 * NSUP;
    const float* sy = sx + NSUP;
    const float* sz = sx + 2 * NSUP;

    const float qx = query_xyz[(size_t)b * 3 * NPOINT + p];
    const float qy = query_xyz[(size_t)b * 3 * NPOINT + NPOINT + p];
    const float qz = query_xyz[(size_t)b * 3 * NPOINT + 2 * NPOINT + p];
    const bool  qm = read_mask(query_mask, b * NPOINT + p, m4q);
    const float qq = (qx * qx + qy * qy) + qz * qz;   // no fma (matches ref)

    // -------- pruned balanced range table (<=16 (z,y) x-runs) --------------
    // lanes 0-15 (run j=lane&15) load run STARTS; lanes 16-31 load run ENDS;
    // exchanged via one shfl — halves the dependent scattered-load chain.
    int T = 0;
    int eT[16], aT[16];   // cumEnd / (rbeg - cumStart), readlane-broadcast
    if (qm) {
        const int x0 = max(0, (int)floorf((qx - 0.101f) * 10.f));
        const int x1 = min(GRID1 - 1, (int)floorf((qx + 0.101f) * 10.f));
        const int y0 = max(0, (int)floorf((qy - 0.101f) * 10.f));
        const int y1 = min(GRID1 - 1, (int)floorf((qy + 0.101f) * 10.f));
        const int z0 = max(0, (int)floorf((qz - 0.101f) * 10.f));
        const int z1 = min(GRID1 - 1, (int)floorf((qz + 0.101f) * 10.f));
        const int* stb = starts + b * (CELLS + 1);

        const int j  = lane & 15;          // run id, mirrored in both halves
        const int jz = j >> 2, jy = j & 3;
        const int cz = z0 + jz,  cy = y0 + jy;
        bool act = (lane < 32) && (cz <= z1) && (cy <= y1);
        int sval = 0;
        if (act) {
            // min distance from query to this run's (y,z) cell footprint
            const float cyl = cy * 0.1f, czl = cz * 0.1f;
            const float dy = fmaxf(0.0f, fmaxf(cyl - qy, qy - (cyl + 0.1f)));
            const float dz = fmaxf(0.0f, fmaxf(czl - qz, qz - (czl + 0.1f)));
            const float rem = 0.0101f - (dy * dy + dz * dz);  // 1e-4 margin
            if (rem < 0.0f) {
                act = false;
            } else {
                // shrink run's x-range: hits need |qx-px| <= sqrt(rem)+eps
                const float mx = sqrtf(rem);
                const int x0r = max(x0, (int)floorf((qx - mx - 0.0005f) * 10.f));
                const int x1r = min(x1, (int)floorf((qx + mx + 0.0005f) * 10.f));
                const int c0 = x0r + GRID1 * cy + GRID1 * GRID1 * cz;
                // never inverted: x0r <= cell(qx) <= x1r (R10-verified)
                sval = (lane < 16) ? stb[c0] : stb[c0 + (x1r - x0r + 1)];
            }
        }
        if (!act) sval = 0;
        const int endv = __shfl(sval, (lane & 15) + 16, 64);
        const int s0   = sval;                       // valid for lane<16
        int len = (lane < 16 && act) ? (endv - s0) : 0;
        // inclusive prefix over lanes 0..15 only (runs live there)
        int pre = len;
        #pragma unroll
        for (int d = 1; d < 16; d <<= 1) {
            const int v = __shfl_up(pre, d, 64);
            if (lane >= d) pre += v;
        }
        const int adj = s0 - (pre - len);  // rbeg - cumStart
        #pragma unroll
        for (int jj = 0; jj < 16; ++jj) {
            eT[jj] = __builtin_amdgcn_readlane(pre, jj);
            aT[jj] = __builtin_amdgcn_readlane(adj, jj);
        }
        T = eT[15];
    }

    // -------- candidate loop, 2-deep pipelined ----------------------------
    const float4* ptsb = pts + (size_t)b * NSUP;
    auto resolve = [&](int g) {
        int adjv = 0;
        #pragma unroll
        for (int jj = 15; jj >= 0; --jj)   // smallest jj with g < eT[jj]
            if (g < eT[jj]) adjv = aT[jj];
        return g + adjv;
    };
    int cnt = 0;
    float4 pv;
    if (T > 0) pv = ptsb[(lane < T) ? resolve(lane) : 0];
    for (int tb = 0; tb < T; tb += 64) {
        float4 nx;
        const int tb2 = tb + 64;           // uniform prefetch guard
        if (tb2 < T) {
            const int gn = tb2 + lane;
            nx = ptsb[(gn < T) ? resolve(gn) : 0];
        }
        const bool valid = (tb + lane) < T;
        const int nidx = __float_as_int(pv.w);
        // EXACT R4 membership arithmetic (bit-exact vs ref):
        const float ss  = (pv.x * pv.x + pv.y * pv.y) + pv.z * pv.z;
        const float dot = __builtin_fmaf(qz, pv.z,
                          __builtin_fmaf(qy, pv.y, qx * pv.x));
        const float d2  = (qq + ss) - 2.0f * dot;
        // pts holds ONLY mask-true points (build_grid filters)
        const bool within = valid && (d2 <= 0.01f);
        const unsigned long long bal = __ballot(within);
        if (within) {
            const int r = cnt + __popcll(bal & ((1ull << lane) - 1ull));
            if (r < 64) hits[r] = nidx;
        }
        cnt += __popcll(bal);
        pv = nx;
    }

    if (cnt > 64) {
        // rare overflow: exact ordered linear rescan (R4-verified loop)
        const bool m4s = probe_mask4(support_mask);
        int c2 = 0;
        for (int basei = 0; basei < NSUP; basei += 64) {
            const int n = basei + lane;
            const float x = sx[n], y = sy[n], z = sz[n];
            const bool  m = read_mask(support_mask, b * NSUP + n, m4s);
            const float ss  = (x * x + y * y) + z * z;
            const float dot = __builtin_fmaf(qz, z,
                              __builtin_fmaf(qy, y, qx * x));
            const float d2  = (qq + ss) - 2.0f * dot;
            const bool within = (d2 <= 0.01f) && m;
            const unsigned long long bal = __ballot(within);
            if (within) {
                const int r = c2 + __popcll(bal & ((1ull << lane) - 1ull));
                if (r < NS) slots[r] = n;
            }
            c2 += __popcll(bal);
            if (c2 >= NS) break;
        }
        cnt = c2;
    } else {
        // bitonic sort, 64 lanes ascending (R6-verified); empties = INT_MAX
        int v = (lane < cnt) ? hits[lane] : 0x7FFFFFFF;
        #pragma unroll
        for (int k = 2; k <= 64; k <<= 1) {
            #pragma unroll
            for (int j2 = k >> 1; j2 > 0; j2 >>= 1) {
                const int pv2 = __shfl_xor(v, j2, 64);
                const bool keep_min = ((lane & j2) == 0) == ((lane & k) == 0);
                const int mn = min(v, pv2), mx = max(v, pv2);
                v = keep_min ? mn : mx;
            }
        }
        if (lane < NS && lane < cnt) slots[lane] = v;
    }
    const int found = (cnt < NS) ? cnt : NS;

    // same-wave LDS: in-order, no barrier needed
    const int first = (found > 0) ? slots[0] : 0;
    if (lane < NS && lane >= found) slots[lane] = first;

    // padded idx -> ws (consumed by gather_feat)
    if (lane < NS) idx_ws[((size_t)b * NPOINT + p) * NS + lane] = slots[lane];

    // idx_mask (f32 0/1) after new_features
    const size_t nf_elems = (size_t)B * 67 * NPOINT * NS;
    if (lane < NS) {
        out[nf_elems + ((size_t)b * NPOINT + p) * NS + lane] =
            (lane < found) ? 1.0f : 0.0f;
    }

    // xyz channels (ch 0..2): 96 elements per query
    for (int i = 0; i < 2; ++i) {
        const int flat = i * 64 + lane;
        if (flat < 3 * NS) {
            const int ch = flat >> 5;
            const int k  = flat & 31;
            const int idx = slots[k];
            const float s = sx[(size_t)ch * NSUP + idx];
            const float q = (ch == 0) ? qx : ((ch == 1) ? qy : qz);
            out[(((size_t)b * 67 + ch) * NPOINT + p) * NS + k] = (s - q) / 0.1f;
        }
    }
}

// ---------- gather: one (b,ch) feature row in LDS, coalesced in/out ---------
__global__ __launch_bounds__(512) void gather_feat(
    const float* __restrict__ features, const int* __restrict__ idx_ws,
    float* __restrict__ out, int B)
{
    __shared__ float row[NSUP];                       // 32 KB
    const int bc = blockIdx.y;                        // b*NCH + ch
    const int b  = bc / NCH, ch = bc % NCH;

    const float* src = features + ((size_t)b * NCH + ch) * NSUP;
    const nvec4* src4 = (const nvec4*)src;
    for (int i = threadIdx.x; i < NSUP / 4; i += 512)
        ((nvec4*)row)[i] = __builtin_nontemporal_load(&src4[i]);
    __syncthreads();

    const int4* idx4 = (const int4*)(idx_ws + ((size_t)b * NPOINT) * NS);
    nvec4* dst4 = (nvec4*)(out + (((size_t)b * 67 + 3 + ch) * NPOINT) * NS);
    for (int e = threadIdx.x; e < QCHUNK * NS / 4; e += 512) {
        const int4 iv = idx4[e];
        nvec4 g;
        g.x = row[iv.x]; g.y = row[iv.y]; g.z = row[iv.z]; g.w = row[iv.w];
        __builtin_nontemporal_store(g, &dst4[e]);     // out never re-read
    }
}

// ---------- proven R4 linear kernel (fallback if ws tiny) ----------
__global__ __launch_bounds__(256) void mqag_linear(
    const float* __restrict__ query_xyz, const float* __restrict__ support_xyz,
    const void* __restrict__ query_mask_raw, const void* __restrict__ support_mask_raw,
    const float* __restrict__ features, float* __restrict__ out, int B)
{
#pragma clang fp contract(off)
    const int wib  = threadIdx.x >> 6;
    const int lane = threadIdx.x & 63;
    const int qid  = blockIdx.x * 4 + wib;
    const int b    = qid / NPOINT;
    const int p    = qid % NPOINT;

    __shared__ int slots_all[4][NS];
    int* slots = slots_all[wib];

    const bool m4s = probe_mask4(support_mask_raw);
    const bool m4q = probe_mask4(query_mask_raw);

    const float* sx = support_xyz + (size_t)b * 3 * NSUP;
    const float* sy = sx + NSUP;
    const float* sz = sx + 2 * NSUP;

    const float qx = query_xyz[(size_t)b * 3 * NPOINT + p];
    const float qy = query_xyz[(size_t)b * 3 * NPOINT + NPOINT + p];
    const float qz = query_xyz[(size_t)b * 3 * NPOINT + 2 * NPOINT + p];
    const bool  qm = read_mask(query_mask_raw, b * NPOINT + p, m4q);
    const float qq = (qx * qx + qy * qy) + qz * qz;

    int cnt = 0;
    if (qm) {
        for (int base = 0; base < NSUP; base += 64) {
            const int n = base + lane;
            const float x = sx[n], y = sy[n], z = sz[n];
            const bool  m = read_mask(support_mask_raw, b * NSUP + n, m4s);
            const float ss  = (x * x + y * y) + z * z;
            const float dot = __builtin_fmaf(qz, z, __builtin_fmaf(qy, y, qx * x));
            const float d2  = (qq + ss) - 2.0f * dot;
            const bool within = (d2 <= 0.01f) && m;
            const unsigned long long bal = __ballot(within);
            if (within) {
                const int r = cnt + __popcll(bal & ((1ull << lane) - 1ull));
                if (r < NS) slots[r] = n;
            }
            cnt += __popcll(bal);
            if (cnt >= NS) break;
        }
    }
    const int found = cnt < NS ? cnt : NS;
    __syncthreads();
    const int first = (found > 0) ? slots[0] : 0;
    if (lane < NS && lane >= found) slots[lane] = first;
    __syncthreads();

    const size_t nf_elems = (size_t)B * 67 * NPOINT * NS;
    if (lane < NS) {
        out[nf_elems + ((size_t)b * NPOINT + p) * NS + lane] =
            (lane < found) ? 1.0f : 0.0f;
    }
    const float* feat = features + (size_t)b * NCH * NSUP;
    for (int i = 0; i < (67 * NS + 63) / 64; ++i) {
        const int flat = i * 64 + lane;
        if (flat < 67 * NS) {
            const int ch = flat >> 5;
            const int k  = flat & 31;
            const int idx = slots[k];
            float val;
            if (ch < 3) {
                const float s = sx[(size_t)ch * NSUP + idx];
                const float q = (ch == 0) ? qx : ((ch == 1) ? qy : qz);
                val = (s - q) / 0.1f;
            } else {
                val = feat[(size_t)(ch - 3) * NSUP + idx];
            }
            out[(((size_t)b * 67 + ch) * NPOINT + p) * NS + k] = val;
        }
    }
}

extern "C" void kernel_launch(void* const* d_in, const int* in_sizes, int n_in,
                              void* d_out, int out_size, void* d_ws, size_t ws_size,
                              hipStream_t stream) {
    const float* query_xyz    = (const float*)d_in[0];
    const float* support_xyz  = (const float*)d_in[1];
    const void*  query_mask   = d_in[2];
    const void*  support_mask = d_in[3];
    const float* features     = (const float*)d_in[4];

    const int B = in_sizes[0] / (3 * NPOINT);      // = 4

    // ws layout: pts | starts | idx   (cursors live in LDS)
    const size_t off_pts    = 0;
    const size_t off_starts = off_pts + (size_t)B * NSUP * sizeof(float4);
    const size_t off_idx    = off_starts + (size_t)B * (CELLS + 1) * sizeof(int);
    const size_t need = off_idx + (size_t)B * NPOINT * NS * sizeof(int);

    if (ws_size >= need) {
        float4* pts  = (float4*)((char*)d_ws + off_pts);
        int* starts  = (int*)((char*)d_ws + off_starts);
        int* idx_ws  = (int*)((char*)d_ws + off_idx);

        hipLaunchKernelGGL(build_grid, dim3(B), dim3(1024), 0, stream,
                           support_xyz, support_mask, starts, pts);
        hipLaunchKernelGGL(mqag_query, dim3(B * NPOINT / 4), dim3(256), 0,
                           stream, query_xyz, support_xyz, query_mask,
                           support_mask, pts, starts, idx_ws, (float*)d_out, B);
        hipLaunchKernelGGL(gather_feat, dim3(1, B * NCH), dim3(512),
                           0, stream, features, idx_ws, (float*)d_out, B);
    } else {
        hipLaunchKernelGGL(mqag_linear, dim3(B * NPOINT / 4), dim3(256), 0,
                           stream, query_xyz, support_xyz, query_mask,
                           support_mask, features, (float*)d_out, B);
    }
}

// Round 5
// 114.147 us; speedup vs baseline: 1.0349x; 1.0349x over previous
//
#include <hip/hip_runtime.h>

// MaskedQueryAndGroup — masked ordered ball query + grouping.
// Shapes: B=4, NPOINT=2048, N=8192, C=64, NSAMPLE=32, R=0.1.
//
// Evidence log:
//  R1-R3: fp32 dataset; masks readable as int32; out = new_features
//    (B,67,NPOINT,32) ++ idx_mask (B,NPOINT,32), both f32.
//  R4 PASSED absmax 0.0: dot = fma(qz,z,fma(qy,y,qx*x)), ss/qq plain mul+add,
//    d2=(qq+ss)-2*dot, contract off. DO NOT change d2 arithmetic.
//  R5 FAILED: shfl_up+binary-search load balancer lost candidates. Avoid.
//  R6 PASSED 159.5: grid + x-run enumeration + bitonic sort all verified.
//  R7 PASSED 129.1: parallel build + feat transpose + LDS-bounce gather.
//  R8 PASSED 123.3: gather via per-(b,ch)-row LDS bounce (QCHUNK=1024,
//    256thr, 512 blocks). Harness fixed cost ~58us fills + ~10-20us of tiny
//    reset dispatches/launch gaps.
//  R9 PASSED 116.6 (pred 100): fused build + balanced 16-run enumeration.
//  R10 PASSED 114.6 (pred 104): barrier-free query + per-run prune + 2-deep
//    pipeline. PROVEN BEST structure.
//  R11 FAILED COMPILE: __builtin_nontemporal_* rejects HIP_vector_type.
//  R12 PASSED 118.1 (pred 109) — REGRESSION +3.5 vs R10. Attribution:
//    gather 256blk x 512thr = 1 block/CU (no load/gather overlap) +
//    nontemporal stores; query split-load was premise-false (R10's two stb
//    loads were already parallel). Build vectorization = the one sound piece.
//  R13 (this): revert to R10 exactly (query + gather), keep ONLY R12's
//    vectorized build loads. Predict 112-114. If >=112: remaining slack is
//    launch-gap floor; then either cooperative mega-fusion or stop.

#define NPOINT 2048
#define NSUP   8192
#define NCH    64
#define NS     32
#define GRID1  10
#define CELLS  1000   // 10*10*10
#define QCHUNK 1024   // queries per gather block (R10-proven)

// ---------- helpers ----------
__device__ __forceinline__ bool probe_mask4(const void* mask) {
    // int32/f32 masks have byte 4i+1 == 0 always; byte bools ~90% nonzero.
    const unsigned char* mb = (const unsigned char*)mask;
    const int lane = threadIdx.x & 63;
    return __ballot(mb[4 * lane + 1] != 0) == 0ull;
}
__device__ __forceinline__ bool read_mask(const void* mask, int i, bool is4) {
    return is4 ? (((const int*)mask)[i] != 0)
               : (((const unsigned char*)mask)[i] != 0);
}
__device__ __forceinline__ int cell_of(float x, float y, float z) {
    const int cx = min(GRID1 - 1, (int)(x * 10.0f));
    const int cy = min(GRID1 - 1, (int)(y * 10.0f));
    const int cz = min(GRID1 - 1, (int)(z * 10.0f));
    return cx + GRID1 * cy + GRID1 * GRID1 * cz;
}

// ---------- fused build: hist + scan + fill in one kernel (1 block/batch) ----
__global__ __launch_bounds__(1024) void build_grid(
    const float* __restrict__ support_xyz, const void* __restrict__ support_mask,
    int* __restrict__ starts, float4* __restrict__ pts)
{
    __shared__ int hist[CELLS];
    __shared__ int scanb[CELLS];
    __shared__ int cur[CELLS];
    __shared__ int wavesum[16];
    const int b    = blockIdx.x;
    const int tid  = threadIdx.x;
    const int wid  = tid >> 6;
    const int lane = tid & 63;
    const bool m4 = probe_mask4(support_mask);
    const float* sx = support_xyz + (size_t)b * 3 * NSUP;

    if (tid < CELLS) { hist[tid] = 0; cur[tid] = 0; }
    __syncthreads();

    // 8 CONSECUTIVE points per thread via vector loads (G13, R12-verified).
    const float4* x4 = (const float4*)sx;
    const float4* y4 = (const float4*)(sx + NSUP);
    const float4* z4 = (const float4*)(sx + 2 * NSUP);
    const float4 xa = x4[tid * 2], xb = x4[tid * 2 + 1];
    const float4 ya = y4[tid * 2], yb = y4[tid * 2 + 1];
    const float4 za = z4[tid * 2], zb = z4[tid * 2 + 1];
    unsigned mk;
    if (m4) {
        const int4* mi4 = (const int4*)((const int*)support_mask + (size_t)b * NSUP);
        const int4 ma = mi4[tid * 2], mb2 = mi4[tid * 2 + 1];
        mk = (ma.x  != 0 ? 1u   : 0u) | (ma.y  != 0 ? 2u   : 0u)
           | (ma.z  != 0 ? 4u   : 0u) | (ma.w  != 0 ? 8u   : 0u)
           | (mb2.x != 0 ? 16u  : 0u) | (mb2.y != 0 ? 32u  : 0u)
           | (mb2.z != 0 ? 64u  : 0u) | (mb2.w != 0 ? 128u : 0u);
    } else {
        const unsigned char* mb = (const unsigned char*)support_mask
                                + (size_t)b * NSUP + (size_t)tid * 8;
        const unsigned lo = *(const unsigned*)(mb);
        const unsigned hi = *(const unsigned*)(mb + 4);
        mk = ((lo & 0xffu)        ? 1u   : 0u) | ((lo & 0xff00u)     ? 2u   : 0u)
           | ((lo & 0xff0000u)    ? 4u   : 0u) | ((lo & 0xff000000u) ? 8u   : 0u)
           | ((hi & 0xffu)        ? 16u  : 0u) | ((hi & 0xff00u)     ? 32u  : 0u)
           | ((hi & 0xff0000u)    ? 64u  : 0u) | ((hi & 0xff000000u) ? 128u : 0u);
    }
    const float xr[8] = {xa.x, xa.y, xa.z, xa.w, xb.x, xb.y, xb.z, xb.w};
    const float yr[8] = {ya.x, ya.y, ya.z, ya.w, yb.x, yb.y, yb.z, yb.w};
    const float zr[8] = {za.x, za.y, za.z, za.w, zb.x, zb.y, zb.z, zb.w};
    int cidr[8];
    #pragma unroll
    for (int i = 0; i < 8; ++i) {
        cidr[i] = cell_of(xr[i], yr[i], zr[i]);
        if ((mk >> i) & 1u) atomicAdd(&hist[cidr[i]], 1);
    }
    __syncthreads();

    // 3-level wave scan (2 barriers): wave-scan64 -> scan16 sums -> add base
    int v = (tid < CELLS) ? hist[tid] : 0;
    #pragma unroll
    for (int d = 1; d < 64; d <<= 1) {
        const int u = __shfl_up(v, d, 64);
        if (lane >= d) v += u;
    }
    if (lane == 63) wavesum[wid] = v;
    __syncthreads();
    if (wid == 0) {
        int w = (lane < 16) ? wavesum[lane] : 0;
        #pragma unroll
        for (int d = 1; d < 16; d <<= 1) {
            const int u = __shfl_up(w, d, 64);
            if (lane >= d) w += u;
        }
        if (lane < 16) wavesum[lane] = w;
    }
    __syncthreads();
    if (wid > 0) v += wavesum[wid - 1];
    // starts[b][0]=0; starts[b][c+1]=inclusive_sum(counts[0..c])
    int* stg = starts + b * (CELLS + 1);
    if (tid == 0) stg[0] = 0;
    if (tid < CELLS) { stg[tid + 1] = v; scanb[tid] = v; }
    __syncthreads();

    // fill via LDS cursors (within-cell order arbitrary; sort-invariant)
    #pragma unroll
    for (int i = 0; i < 8; ++i) {
        if ((mk >> i) & 1u) {
            const int c    = cidr[i];
            const int base = (c == 0) ? 0 : scanb[c - 1];
            const int pos  = base + atomicAdd(&cur[c], 1);
            pts[(size_t)b * NSUP + pos] =
                make_float4(xr[i], yr[i], zr[i], __int_as_float(tid * 8 + i));
        }
    }
}

// ---------- query: pruned balanced scan + sort, barrier-free (4 q/block) ----
// R10-proven version, byte-identical.
__global__ __launch_bounds__(256) void mqag_query(
    const float* __restrict__ query_xyz, const float* __restrict__ support_xyz,
    const void* __restrict__ query_mask, const void* __restrict__ support_mask,
    const float4* __restrict__ pts, const int* __restrict__ starts,
    int* __restrict__ idx_ws, float* __restrict__ out, int B)
{
#pragma clang fp contract(off)
    const int wib  = threadIdx.x >> 6;
    const int lane = threadIdx.x & 63;
    const int qid  = blockIdx.x * 4 + wib;
    const int b    = qid / NPOINT;
    const int p    = qid % NPOINT;

    // wave-private LDS slices: NO block barriers anywhere in this kernel.
    __shared__ int hits_all[4][64];
    __shared__ int slots_all[4][NS];
    int* hits  = hits_all[wib];
    int* slots = slots_all[wib];

    const bool m4q = probe_mask4(query_mask);

    const float* sx = support_xyz + (size_t)b * 3 * NSUP;
    const float* sy = sx + NSUP;
    const float* sz = sx + 2 * NSUP;

    const float qx = query_xyz[(size_t)b * 3 * NPOINT + p];
    const float qy = query_xyz[(size_t)b * 3 * NPOINT + NPOINT + p];
    const float qz = query_xyz[(size_t)b * 3 * NPOINT + 2 * NPOINT + p];
    const bool  qm = read_mask(query_mask, b * NPOINT + p, m4q);
    const float qq = (qx * qx + qy * qy) + qz * qz;   // no fma (matches ref)

    // -------- pruned balanced range table (<=16 (z,y) x-runs) --------------
    int T = 0;
    int eT[16], aT[16];   // cumEnd / (rbeg - cumStart), readlane-broadcast
    if (qm) {
        const int x0 = max(0, (int)floorf((qx - 0.101f) * 10.f));
        const int x1 = min(GRID1 - 1, (int)floorf((qx + 0.101f) * 10.f));
        const int y0 = max(0, (int)floorf((qy - 0.101f) * 10.f));
        const int y1 = min(GRID1 - 1, (int)floorf((qy + 0.101f) * 10.f));
        const int z0 = max(0, (int)floorf((qz - 0.101f) * 10.f));
        const int z1 = min(GRID1 - 1, (int)floorf((qz + 0.101f) * 10.f));
        const int* stb = starts + b * (CELLS + 1);

        // lane j<16 owns run (jz=j>>2, jy=j&3); span <=4 cells/dim
        const int jz = lane >> 2, jy = lane & 3;
        const int cz = z0 + jz,  cy = y0 + jy;
        bool act = (lane < 16) && (cz <= z1) && (cy <= y1);
        int len = 0, s0 = 0;
        if (act) {
            // min distance from query to this run's (y,z) cell footprint
            const float cyl = cy * 0.1f, czl = cz * 0.1f;
            const float dy = fmaxf(0.0f, fmaxf(cyl - qy, qy - (cyl + 0.1f)));
            const float dz = fmaxf(0.0f, fmaxf(czl - qz, qz - (czl + 0.1f)));
            const float rem = 0.0101f - (dy * dy + dz * dz);  // 1e-4 margin
            if (rem < 0.0f) {
                act = false;
            } else {
                // shrink run's x-range: hits need |qx-px| <= sqrt(rem)+eps
                const float mx = sqrtf(rem);
                const int x0r = max(x0, (int)floorf((qx - mx - 0.0005f) * 10.f));
                const int x1r = min(x1, (int)floorf((qx + mx + 0.0005f) * 10.f));
                const int c0 = x0r + GRID1 * cy + GRID1 * GRID1 * cz;
                s0  = stb[c0];
                len = stb[c0 + (x1r - x0r + 1)] - s0;  // x-contiguous (R6)
            }
        }
        if (!act) { len = 0; s0 = 0; }
        // inclusive prefix over lanes 0..15 only (runs live there)
        int pre = len;
        #pragma unroll
        for (int d = 1; d < 16; d <<= 1) {
            const int v = __shfl_up(pre, d, 64);
            if (lane >= d) pre += v;
        }
        const int adj = s0 - (pre - len);  // rbeg - cumStart
        #pragma unroll
        for (int j = 0; j < 16; ++j) {
            eT[j] = __builtin_amdgcn_readlane(pre, j);
            aT[j] = __builtin_amdgcn_readlane(adj, j);
        }
        T = eT[15];
    }

    // -------- candidate loop, 2-deep pipelined ----------------------------
    const float4* ptsb = pts + (size_t)b * NSUP;
    auto resolve = [&](int g) {
        int adjv = 0;
        #pragma unroll
        for (int jj = 15; jj >= 0; --jj)   // smallest jj with g < eT[jj]
            if (g < eT[jj]) adjv = aT[jj];
        return g + adjv;
    };
    int cnt = 0;
    float4 pv;
    if (T > 0) pv = ptsb[(lane < T) ? resolve(lane) : 0];
    for (int tb = 0; tb < T; tb += 64) {
        float4 nx;
        const int tb2 = tb + 64;           // uniform prefetch guard
        if (tb2 < T) {
            const int gn = tb2 + lane;
            nx = ptsb[(gn < T) ? resolve(gn) : 0];
        }
        const bool valid = (tb + lane) < T;
        const int nidx = __float_as_int(pv.w);
        // EXACT R4 membership arithmetic (bit-exact vs ref):
        const float ss  = (pv.x * pv.x + pv.y * pv.y) + pv.z * pv.z;
        const float dot = __builtin_fmaf(qz, pv.z,
                          __builtin_fmaf(qy, pv.y, qx * pv.x));
        const float d2  = (qq + ss) - 2.0f * dot;
        // pts holds ONLY mask-true points (build_grid filters)
        const bool within = valid && (d2 <= 0.01f);
        const unsigned long long bal = __ballot(within);
        if (within) {
            const int r = cnt + __popcll(bal & ((1ull << lane) - 1ull));
            if (r < 64) hits[r] = nidx;
        }
        cnt += __popcll(bal);
        pv = nx;
    }

    if (cnt > 64) {
        // rare overflow: exact ordered linear rescan (R4-verified loop)
        const bool m4s = probe_mask4(support_mask);
        int c2 = 0;
        for (int basei = 0; basei < NSUP; basei += 64) {
            const int n = basei + lane;
            const float x = sx[n], y = sy[n], z = sz[n];
            const bool  m = read_mask(support_mask, b * NSUP + n, m4s);
            const float ss  = (x * x + y * y) + z * z;
            const float dot = __builtin_fmaf(qz, z,
                              __builtin_fmaf(qy, y, qx * x));
            const float d2  = (qq + ss) - 2.0f * dot;
            const bool within = (d2 <= 0.01f) && m;
            const unsigned long long bal = __ballot(within);
            if (within) {
                const int r = c2 + __popcll(bal & ((1ull << lane) - 1ull));
                if (r < NS) slots[r] = n;
            }
            c2 += __popcll(bal);
            if (c2 >= NS) break;
        }
        cnt = c2;
    } else {
        // bitonic sort, 64 lanes ascending (R6-verified); empties = INT_MAX
        int v = (lane < cnt) ? hits[lane] : 0x7FFFFFFF;
        #pragma unroll
        for (int k = 2; k <= 64; k <<= 1) {
            #pragma unroll
            for (int j2 = k >> 1; j2 > 0; j2 >>= 1) {
                const int pv2 = __shfl_xor(v, j2, 64);
                const bool keep_min = ((lane & j2) == 0) == ((lane & k) == 0);
                const int mn = min(v, pv2), mx = max(v, pv2);
                v = keep_min ? mn : mx;
            }
        }
        if (lane < NS && lane < cnt) slots[lane] = v;
    }
    const int found = (cnt < NS) ? cnt : NS;

    // same-wave LDS: in-order, no barrier needed
    const int first = (found > 0) ? slots[0] : 0;
    if (lane < NS && lane >= found) slots[lane] = first;

    // padded idx -> ws (consumed by gather_feat)
    if (lane < NS) idx_ws[((size_t)b * NPOINT + p) * NS + lane] = slots[lane];

    // idx_mask (f32 0/1) after new_features
    const size_t nf_elems = (size_t)B * 67 * NPOINT * NS;
    if (lane < NS) {
        out[nf_elems + ((size_t)b * NPOINT + p) * NS + lane] =
            (lane < found) ? 1.0f : 0.0f;
    }

    // xyz channels (ch 0..2): 96 elements per query
    for (int i = 0; i < 2; ++i) {
        const int flat = i * 64 + lane;
        if (flat < 3 * NS) {
            const int ch = flat >> 5;
            const int k  = flat & 31;
            const int idx = slots[k];
            const float s = sx[(size_t)ch * NSUP + idx];
            const float q = (ch == 0) ? qx : ((ch == 1) ? qy : qz);
            out[(((size_t)b * 67 + ch) * NPOINT + p) * NS + k] = (s - q) / 0.1f;
        }
    }
}

// ---------- gather: one (b,ch) feature row in LDS, coalesced in/out ---------
// R8/R10-proven config: QCHUNK=1024, 256 threads, 512 blocks.
__global__ __launch_bounds__(256) void gather_feat(
    const float* __restrict__ features, const int* __restrict__ idx_ws,
    float* __restrict__ out, int B)
{
    __shared__ float row[NSUP];                       // 32 KB
    const int bc = blockIdx.y;                        // b*NCH + ch
    const int b  = bc / NCH, ch = bc % NCH;
    const int p0 = blockIdx.x * QCHUNK;

    const float* src = features + ((size_t)b * NCH + ch) * NSUP;
    const float4* src4 = (const float4*)src;
    for (int i = threadIdx.x; i < NSUP / 4; i += 256)
        ((float4*)row)[i] = src4[i];
    __syncthreads();

    const int4* idx4 = (const int4*)(idx_ws + ((size_t)b * NPOINT + p0) * NS);
    float4* dst4 = (float4*)(out + (((size_t)b * 67 + 3 + ch) * NPOINT + p0) * NS);
    for (int e = threadIdx.x; e < QCHUNK * NS / 4; e += 256) {
        const int4 iv = idx4[e];
        dst4[e] = make_float4(row[iv.x], row[iv.y], row[iv.z], row[iv.w]);
    }
}

// ---------- proven R4 linear kernel (fallback if ws tiny) ----------
__global__ __launch_bounds__(256) void mqag_linear(
    const float* __restrict__ query_xyz, const float* __restrict__ support_xyz,
    const void* __restrict__ query_mask_raw, const void* __restrict__ support_mask_raw,
    const float* __restrict__ features, float* __restrict__ out, int B)
{
#pragma clang fp contract(off)
    const int wib  = threadIdx.x >> 6;
    const int lane = threadIdx.x & 63;
    const int qid  = blockIdx.x * 4 + wib;
    const int b    = qid / NPOINT;
    const int p    = qid % NPOINT;

    __shared__ int slots_all[4][NS];
    int* slots = slots_all[wib];

    const bool m4s = probe_mask4(support_mask_raw);
    const bool m4q = probe_mask4(query_mask_raw);

    const float* sx = support_xyz + (size_t)b * 3 * NSUP;
    const float* sy = sx + NSUP;
    const float* sz = sx + 2 * NSUP;

    const float qx = query_xyz[(size_t)b * 3 * NPOINT + p];
    const float qy = query_xyz[(size_t)b * 3 * NPOINT + NPOINT + p];
    const float qz = query_xyz[(size_t)b * 3 * NPOINT + 2 * NPOINT + p];
    const bool  qm = read_mask(query_mask_raw, b * NPOINT + p, m4q);
    const float qq = (qx * qx + qy * qy) + qz * qz;

    int cnt = 0;
    if (qm) {
        for (int base = 0; base < NSUP; base += 64) {
            const int n = base + lane;
            const float x = sx[n], y = sy[n], z = sz[n];
            const bool  m = read_mask(support_mask_raw, b * NSUP + n, m4s);
            const float ss  = (x * x + y * y) + z * z;
            const float dot = __builtin_fmaf(qz, z, __builtin_fmaf(qy, y, qx * x));
            const float d2  = (qq + ss) - 2.0f * dot;
            const bool within = (d2 <= 0.01f) && m;
            const unsigned long long bal = __ballot(within);
            if (within) {
                const int r = cnt + __popcll(bal & ((1ull << lane) - 1ull));
                if (r < NS) slots[r] = n;
            }
            cnt += __popcll(bal);
            if (cnt >= NS) break;
        }
    }
    const int found = cnt < NS ? cnt : NS;
    __syncthreads();
    const int first = (found > 0) ? slots[0] : 0;
    if (lane < NS && lane >= found) slots[lane] = first;
    __syncthreads();

    const size_t nf_elems = (size_t)B * 67 * NPOINT * NS;
    if (lane < NS) {
        out[nf_elems + ((size_t)b * NPOINT + p) * NS + lane] =
            (lane < found) ? 1.0f : 0.0f;
    }
    const float* feat = features + (size_t)b * NCH * NSUP;
    for (int i = 0; i < (67 * NS + 63) / 64; ++i) {
        const int flat = i * 64 + lane;
        if (flat < 67 * NS) {
            const int ch = flat >> 5;
            const int k  = flat & 31;
            const int idx = slots[k];
            float val;
            if (ch < 3) {
                const float s = sx[(size_t)ch * NSUP + idx];
                const float q = (ch == 0) ? qx : ((ch == 1) ? qy : qz);
                val = (s - q) / 0.1f;
            } else {
                val = feat[(size_t)(ch - 3) * NSUP + idx];
            }
            out[(((size_t)b * 67 + ch) * NPOINT + p) * NS + k] = val;
        }
    }
}

extern "C" void kernel_launch(void* const* d_in, const int* in_sizes, int n_in,
                              void* d_out, int out_size, void* d_ws, size_t ws_size,
                              hipStream_t stream) {
    const float* query_xyz    = (const float*)d_in[0];
    const float* support_xyz  = (const float*)d_in[1];
    const void*  query_mask   = d_in[2];
    const void*  support_mask = d_in[3];
    const float* features     = (const float*)d_in[4];

    const int B = in_sizes[0] / (3 * NPOINT);      // = 4

    // ws layout: pts | starts | idx   (cursors live in LDS)
    const size_t off_pts    = 0;
    const size_t off_starts = off_pts + (size_t)B * NSUP * sizeof(float4);
    const size_t off_idx    = off_starts + (size_t)B * (CELLS + 1) * sizeof(int);
    const size_t need = off_idx + (size_t)B * NPOINT * NS * sizeof(int);

    if (ws_size >= need) {
        float4* pts  = (float4*)((char*)d_ws + off_pts);
        int* starts  = (int*)((char*)d_ws + off_starts);
        int* idx_ws  = (int*)((char*)d_ws + off_idx);

        hipLaunchKernelGGL(build_grid, dim3(B), dim3(1024), 0, stream,
                           support_xyz, support_mask, starts, pts);
        hipLaunchKernelGGL(mqag_query, dim3(B * NPOINT / 4), dim3(256), 0,
                           stream, query_xyz, support_xyz, query_mask,
                           support_mask, pts, starts, idx_ws, (float*)d_out, B);
        hipLaunchKernelGGL(gather_feat, dim3(NPOINT / QCHUNK, B * NCH), dim3(256),
                           0, stream, features, idx_ws, (float*)d_out, B);
    } else {
        hipLaunchKernelGGL(mqag_linear, dim3(B * NPOINT / 4), dim3(256), 0,
                           stream, query_xyz, support_xyz, query_mask,
                           support_mask, features, (float*)d_out, B);
    }
}